// Round 5
// baseline (846.306 us; speedup 1.0000x reference)
//
#include <hip/hip_runtime.h>
#include <hip/hip_cooperative_groups.h>

namespace cg = cooperative_groups;

// D=4096, H=2 (head_dim 2048), E=8192, OUT=1, L=2, batch 1.
// R3/R4 lesson: three different multi-kernel structures all ~509-529 us ->
// fixed inter-dispatch cost dominates, not GEMV micro-structure.
// This round: ONE cooperative kernel, 6 grid.sync()s, zero intermediate launches.
// Roofline: 537 MB weights @ ~6.3 TB/s ~= 85 us + ~6 syncs (~20-40 us).
#define D4 4096
#define E8 8192
#define NBLK 256
#define NTHR 1024
#define NWAVES (NBLK * (NTHR / 64))   // 4096 waves

// g_ws layout (fp32 elems). Every element written before read each call.
#define OFF_X    0        // x[2][4096]      (residual source)
#define OFF_QKV  8192     // qkv[2][12288]
#define OFF_XO   32768    // xo[2][4096]     (post-attn residual stream)
#define OFF_H    40960    // h[2][4096]
#define OFF_X2   49152    // x2[2][4096]
#define OFF_G    57344    // g[2][8192]
#define OFF_S    73728    // 8 raw attention scores
__device__ float g_ws[73744];

struct P {
    const float *ray, *e1w, *e1b, *e2w, *e2b;
    const float *aiw, *aib, *aow, *aob;
    const float *f1w, *f1b, *f2w, *f2b;
    const float *xw1, *xb1, *xw2, *xb2;
    float *out;
};

// 2-token GEMV over rows r = gwave, gwave+NWAVES, ... ; x resides in LDS (sx).
// Per row: 2 bursts of 8 float4 weight loads (128 B/lane outstanding) + LDS x,
// wave shfl-reduce, lane0 epilogue (bias/resid/relu) and token-major store.
__device__ __forceinline__ void gemv2_lds(
        const float* __restrict__ W, const float* __restrict__ bias,
        const float* sx, float* out, const float* resid,
        int R, int relu, int lane, int gwave)
{
    for (int r = gwave; r < R; r += NWAVES) {
        const float* wrow = W + (size_t)r * D4;
        float a0 = 0.f, a1 = 0.f;
        #pragma unroll
        for (int c = 0; c < 2; ++c) {
            float4 wv[8];
            #pragma unroll
            for (int k = 0; k < 8; ++k)
                wv[k] = *(const float4*)(wrow + ((c * 8 + k) * 64 + lane) * 4);
            #pragma unroll
            for (int k = 0; k < 8; ++k) {
                int j = ((c * 8 + k) * 64 + lane) * 4;
                float4 x0 = *(const float4*)(sx + j);
                float4 x1 = *(const float4*)(sx + D4 + j);
                a0 += wv[k].x*x0.x + wv[k].y*x0.y + wv[k].z*x0.z + wv[k].w*x0.w;
                a1 += wv[k].x*x1.x + wv[k].y*x1.y + wv[k].z*x1.z + wv[k].w*x1.w;
            }
        }
        #pragma unroll
        for (int off = 32; off; off >>= 1) {
            a0 += __shfl_down(a0, off);
            a1 += __shfl_down(a1, off);
        }
        if (lane == 0) {
            float b = bias[r];
            float r0 = a0 + b, r1 = a1 + b;
            if (resid) { r0 += resid[r]; r1 += resid[R + r]; }
            if (relu)  { r0 = fmaxf(r0, 0.f); r1 = fmaxf(r1, 0.f); }
            out[r] = r0; out[R + r] = r1;
        }
    }
}

__global__ __launch_bounds__(NTHR) void k_fused(P p) {
    cg::grid_group grid = cg::this_grid();
    __shared__ float sx[2 * D4];       // 32 KB staging (x / o / xo / h / x2)
    __shared__ float sred[16];
    __shared__ float sred2[16][2];
    int tid = threadIdx.x, lane = tid & 63, wave = tid >> 6;
    int gwave = blockIdx.x * (NTHR / 64) + wave;

    // ---- Phase B: embed x into LDS (fused, no separate kernel) + QKV GEMV ----
    float r0 = p.ray[0], r1 = p.ray[1];
    #pragma unroll
    for (int it = 0; it < 4; ++it) {
        int i = it * NTHR + tid;
        sx[i]      = fmaxf(fmaf(r0, p.e1w[i], p.e1b[i]), 0.f);
        sx[D4 + i] = fmaxf(fmaf(r1, p.e2w[i], p.e2b[i]), 0.f);
    }
    __syncthreads();
    if (blockIdx.x == 0) {             // persist x for the attn residual
        #pragma unroll
        for (int it = 0; it < 8; ++it) {
            int i = it * NTHR + tid;
            g_ws[OFF_X + i] = sx[i];
        }
    }
    gemv2_lds(p.aiw, p.aib, sx, g_ws + OFF_QKV, nullptr, 3 * D4, 0, lane, gwave);
    grid.sync();

    // ---- Phase C: 8 raw score dots s[h][l][m], one per block 0..7 ----
    if (blockIdx.x < 8) {
        int b = blockIdx.x;
        int h = b >> 2, l = (b >> 1) & 1, m = b & 1;
        const float* q = g_ws + OFF_QKV + l * 3 * D4 + h * 2048;
        const float* k = g_ws + OFF_QKV + m * 3 * D4 + D4 + h * 2048;
        float acc = q[tid * 2] * k[tid * 2] + q[tid * 2 + 1] * k[tid * 2 + 1];
        #pragma unroll
        for (int off = 32; off; off >>= 1) acc += __shfl_down(acc, off);
        if (lane == 0) sred[wave] = acc;
        __syncthreads();
        if (tid == 0) {
            float s = 0.f;
            for (int w = 0; w < 16; ++w) s += sred[w];
            g_ws[OFF_S + b] = s;
        }
    }
    grid.sync();

    // ---- Phase D: softmax probs (uniform), o into LDS, attn_out GEMV + resid x ----
    {
        float scale = rsqrtf(2048.f);
        float pr[2][2][2];             // all accesses static after unroll -> regs
        #pragma unroll
        for (int h = 0; h < 2; ++h)
            #pragma unroll
            for (int l = 0; l < 2; ++l) {
                float s0 = g_ws[OFF_S + h * 4 + l * 2 + 0] * scale;
                float s1 = g_ws[OFF_S + h * 4 + l * 2 + 1] * scale;
                float mx = fmaxf(s0, s1);
                float e0 = __expf(s0 - mx), e1 = __expf(s1 - mx);
                float inv = 1.f / (e0 + e1);
                pr[h][l][0] = e0 * inv; pr[h][l][1] = e1 * inv;
            }
        #pragma unroll
        for (int it = 0; it < 4; ++it) {
            int i = it * NTHR + tid;
            const int h = it >> 1;     // compile-time per unrolled iter
            float v0 = g_ws[OFF_QKV + 0 * 3 * D4 + 2 * D4 + i];
            float v1 = g_ws[OFF_QKV + 1 * 3 * D4 + 2 * D4 + i];
            sx[i]      = pr[h][0][0] * v0 + pr[h][0][1] * v1;
            sx[D4 + i] = pr[h][1][0] * v0 + pr[h][1][1] * v1;
        }
        __syncthreads();
        gemv2_lds(p.aow, p.aob, sx, g_ws + OFF_XO, g_ws + OFF_X, D4, 0, lane, gwave);
    }
    grid.sync();

    // ---- Phase E: h = relu(ffn1 . xo + b) ----
    #pragma unroll
    for (int it = 0; it < 2; ++it) {
        int j = (it * NTHR + tid) * 4;
        *(float4*)(sx + j) = *(const float4*)(g_ws + OFF_XO + j);
    }
    __syncthreads();
    gemv2_lds(p.f1w, p.f1b, sx, g_ws + OFF_H, nullptr, D4, 1, lane, gwave);
    grid.sync();

    // ---- Phase F: x2 = xo + ffn2 . h + b ----
    #pragma unroll
    for (int it = 0; it < 2; ++it) {
        int j = (it * NTHR + tid) * 4;
        *(float4*)(sx + j) = *(const float4*)(g_ws + OFF_H + j);
    }
    __syncthreads();
    gemv2_lds(p.f2w, p.f2b, sx, g_ws + OFF_X2, g_ws + OFF_XO, D4, 0, lane, gwave);
    grid.sync();

    // ---- Phase G: g = relu(exp_w1 . x2 + b1) ----
    #pragma unroll
    for (int it = 0; it < 2; ++it) {
        int j = (it * NTHR + tid) * 4;
        *(float4*)(sx + j) = *(const float4*)(g_ws + OFF_X2 + j);
    }
    __syncthreads();
    gemv2_lds(p.xw1, p.xb1, sx, g_ws + OFF_G, nullptr, E8, 1, lane, gwave);
    grid.sync();

    // ---- Phase H: out = mean_l(exp_w2 . g[l] + b2), block 0 only ----
    if (blockIdx.x == 0) {
        float a0 = 0.f, a1 = 0.f;
        #pragma unroll
        for (int it = 0; it < 8; ++it) {
            int e = it * NTHR + tid;
            float w = p.xw2[e];
            a0 += w * g_ws[OFF_G + e];
            a1 += w * g_ws[OFF_G + E8 + e];
        }
        #pragma unroll
        for (int off = 32; off; off >>= 1) {
            a0 += __shfl_down(a0, off);
            a1 += __shfl_down(a1, off);
        }
        if (lane == 0) { sred2[wave][0] = a0; sred2[wave][1] = a1; }
        __syncthreads();
        if (tid == 0) {
            float y0 = 0.f, y1 = 0.f;
            for (int w = 0; w < 16; ++w) { y0 += sred2[w][0]; y1 += sred2[w][1]; }
            p.out[0] = 0.5f * (y0 + y1) + p.xb2[0];
        }
    }
}

extern "C" void kernel_launch(void* const* d_in, const int* in_sizes, int n_in,
                              void* d_out, int out_size, void* d_ws, size_t ws_size,
                              hipStream_t stream) {
    (void)d_ws; (void)ws_size; (void)in_sizes; (void)n_in;  // idx = d_in[17] unused
    P p;
    p.ray = (const float*)d_in[0];
    p.e1w = (const float*)d_in[1];  p.e1b = (const float*)d_in[2];
    p.e2w = (const float*)d_in[3];  p.e2b = (const float*)d_in[4];
    p.aiw = (const float*)d_in[5];  p.aib = (const float*)d_in[6];
    p.aow = (const float*)d_in[7];  p.aob = (const float*)d_in[8];
    p.f1w = (const float*)d_in[9];  p.f1b = (const float*)d_in[10];
    p.f2w = (const float*)d_in[11]; p.f2b = (const float*)d_in[12];
    p.xw1 = (const float*)d_in[13]; p.xb1 = (const float*)d_in[14];
    p.xw2 = (const float*)d_in[15]; p.xb2 = (const float*)d_in[16];
    p.out = (float*)d_out;

    void* args[] = { &p };
    hipLaunchCooperativeKernel((void*)k_fused, dim3(NBLK), dim3(NTHR),
                               args, 0u, stream);
}

// Round 10
// 513.588 us; speedup vs baseline: 1.6478x; 1.6478x over previous
//
#include <hip/hip_runtime.h>

// D=4096, H=2 (head_dim 2048), E=8192, OUT=1, L=2, batch 1.
// R5 evidence: fused coop kernel = 467us @ 24% HBM, VALU 2.7%, occ 47.7% ->
// memory-stalled at ~7.5 GB/s/CU (issue duty cycle), and coop launch itself
// costs (dur 846 vs 512). Plan: plain chain + half-row-per-wave GEMV:
// one 8-load burst per wave task, 32 waves/CU (launch_bounds(256,8), no LDS).
#define D4 4096
#define E8 8192

// Static device scratch. Every element written before read on every call.
#define OFF_X    0
#define OFF_QKV  8192
#define OFF_O    32768
#define OFF_H    40960
#define OFF_G    49152
__device__ float g_ws[65536];

// x[0][i] = relu(ray0*w1[i]+b1[i]); x[1][i] = relu(ray1*w2[i]+b2[i])
__global__ void k_embed(const float* __restrict__ ray,
                        const float* __restrict__ w1,
                        const float* __restrict__ b1,
                        const float* __restrict__ w2,
                        const float* __restrict__ b2) {
    int i = blockIdx.x * blockDim.x + threadIdx.x;
    if (i < D4) {
        float r0 = ray[0], r1 = ray[1];
        g_ws[OFF_X + i]      = fmaxf(fmaf(r0, w1[i], b1[i]), 0.f);
        g_ws[OFF_X + D4 + i] = fmaxf(fmaf(r1, w2[i], b2[i]), 0.f);
    }
}

// 2-token GEMV, HALF-row per wave. Block = 256 thr = 4 waves = 2 rows.
// Wave w: row = blk*2 + (w>>1), half = w&1; lane loads 8 float4 of W in ONE
// burst (32 VGPR), dots against x (L1/L2-resident, 32 KB), 64-lane shfl
// reduce, LDS combine of the two half-waves, 4-thread parallel epilogue.
// launch_bounds(256,8) -> <=64 VGPR -> 32 waves/CU -> ~256 KB/CU in flight.
__global__ __launch_bounds__(256, 8) void k_gemv_h(
        const float* __restrict__ W,
        const float* __restrict__ bias,
        int xin_off, int out_off, int resid_off,
        int R, int relu_flag) {
    int tid = threadIdx.x, lane = tid & 63, wave = tid >> 6;
    int r  = blockIdx.x * 2 + (wave >> 1);
    int hf = wave & 1;
    const float* wp = W + (size_t)r * D4 + hf * 2048;
    const float* xp = g_ws + xin_off + hf * 2048;

    float4 wv[8];
    #pragma unroll
    for (int k = 0; k < 8; ++k)
        wv[k] = *(const float4*)(wp + (k * 64 + lane) * 4);

    float a0 = 0.f, a1 = 0.f;
    #pragma unroll
    for (int k = 0; k < 8; ++k) {
        int j = (k * 64 + lane) * 4;
        float4 x0 = *(const float4*)(xp + j);
        float4 x1 = *(const float4*)(xp + D4 + j);
        a0 += wv[k].x*x0.x + wv[k].y*x0.y + wv[k].z*x0.z + wv[k].w*x0.w;
        a1 += wv[k].x*x1.x + wv[k].y*x1.y + wv[k].z*x1.z + wv[k].w*x1.w;
    }
    #pragma unroll
    for (int off = 32; off; off >>= 1) {
        a0 += __shfl_down(a0, off);
        a1 += __shfl_down(a1, off);
    }
    __shared__ float sred[4][2];
    if (lane == 0) { sred[wave][0] = a0; sred[wave][1] = a1; }
    __syncthreads();
    if (tid < 4) {
        int rl = tid >> 1, tok = tid & 1;
        int rr = blockIdx.x * 2 + rl;
        float s = sred[rl * 2][tok] + sred[rl * 2 + 1][tok] + bias[rr];
        if (resid_off >= 0) s += g_ws[resid_off + tok * R + rr];
        if (relu_flag) s = fmaxf(s, 0.f);
        g_ws[out_off + tok * R + rr] = s;
    }
}

// Tiny MHA core: qkv fp32 [2, 3*4096] -> o fp32 [2, 4096]. H=2, hd=2048, S=2.
__global__ void k_attn() {
    const int HD = D4 / 2;  // 2048
    const float* qkv = g_ws + OFF_QKV;
    float* o = g_ws + OFF_O;
    __shared__ float sred[8][16];
    __shared__ float sattn[2][2][2];  // [h][l][m]
    int tid = threadIdx.x, lane = tid & 63, wave = tid >> 6;

    float a000 = 0.f, a001 = 0.f, a010 = 0.f, a011 = 0.f;  // h=0
    float a100 = 0.f, a101 = 0.f, a110 = 0.f, a111 = 0.f;  // h=1
    #pragma unroll
    for (int it = 0; it < 2; ++it) {                 // i in [0, 2048): h = 0
        int i = it * 1024 + tid;
        float q0 = qkv[0 * 3 * D4 + i];
        float q1 = qkv[1 * 3 * D4 + i];
        float k0 = qkv[0 * 3 * D4 + D4 + i];
        float k1 = qkv[1 * 3 * D4 + D4 + i];
        a000 += q0 * k0; a001 += q0 * k1;
        a010 += q1 * k0; a011 += q1 * k1;
    }
    #pragma unroll
    for (int it = 0; it < 2; ++it) {                 // i in [2048, 4096): h = 1
        int i = HD + it * 1024 + tid;
        float q0 = qkv[0 * 3 * D4 + i];
        float q1 = qkv[1 * 3 * D4 + i];
        float k0 = qkv[0 * 3 * D4 + D4 + i];
        float k1 = qkv[1 * 3 * D4 + D4 + i];
        a100 += q0 * k0; a101 += q0 * k1;
        a110 += q1 * k0; a111 += q1 * k1;
    }
    #define WREDUCE(v, idx) { float t_ = (v); \
        _Pragma("unroll") \
        for (int off_ = 32; off_; off_ >>= 1) t_ += __shfl_down(t_, off_); \
        if (lane == 0) sred[idx][wave] = t_; }
    WREDUCE(a000, 0) WREDUCE(a001, 1) WREDUCE(a010, 2) WREDUCE(a011, 3)
    WREDUCE(a100, 4) WREDUCE(a101, 5) WREDUCE(a110, 6) WREDUCE(a111, 7)
    #undef WREDUCE
    __syncthreads();
    if (tid == 0) {
        float scale = rsqrtf((float)HD);
        for (int h = 0; h < 2; h++)
            for (int l = 0; l < 2; l++) {
                float s0 = 0.f, s1 = 0.f;
                for (int w = 0; w < 16; w++) {
                    s0 += sred[(h * 2 + l) * 2 + 0][w];
                    s1 += sred[(h * 2 + l) * 2 + 1][w];
                }
                s0 *= scale; s1 *= scale;
                float mx = fmaxf(s0, s1);
                float e0 = __expf(s0 - mx), e1 = __expf(s1 - mx);
                float inv = 1.f / (e0 + e1);
                sattn[h][l][0] = e0 * inv;
                sattn[h][l][1] = e1 * inv;
            }
    }
    __syncthreads();
    #pragma unroll
    for (int it = 0; it < 4; ++it) {
        int i = it * 1024 + tid;
        int h = i >> 11;                             // i / 2048
        float v0 = qkv[0 * 3 * D4 + 2 * D4 + i];
        float v1 = qkv[1 * 3 * D4 + 2 * D4 + i];
        o[i]      = sattn[h][0][0] * v0 + sattn[h][0][1] * v1;
        o[D4 + i] = sattn[h][1][0] * v0 + sattn[h][1][1] * v1;
    }
}

// Final: y[l] = dot(w2, g[l]) + b2; out = fp32 mean over l. 1024 threads.
__global__ void k_expert_out(const float* __restrict__ w2,
                             const float* __restrict__ b2,
                             float* __restrict__ out) {
    const float* g = g_ws + OFF_G;
    __shared__ float sred[2][16];
    int tid = threadIdx.x, lane = tid & 63, wave = tid >> 6;
    float a0 = 0.f, a1 = 0.f;
    #pragma unroll
    for (int it = 0; it < E8 / 1024; ++it) {         // 8 iterations
        int e = it * 1024 + tid;
        float w = w2[e];
        a0 += w * g[e];
        a1 += w * g[E8 + e];
    }
    #pragma unroll
    for (int off = 32; off; off >>= 1) {
        a0 += __shfl_down(a0, off);
        a1 += __shfl_down(a1, off);
    }
    if (lane == 0) { sred[0][wave] = a0; sred[1][wave] = a1; }
    __syncthreads();
    if (tid == 0) {
        float b = b2[0];
        float y0 = b, y1 = b;
        for (int w = 0; w < 16; w++) { y0 += sred[0][w]; y1 += sred[1][w]; }
        out[0] = 0.5f * (y0 + y1);
    }
}

extern "C" void kernel_launch(void* const* d_in, const int* in_sizes, int n_in,
                              void* d_out, int out_size, void* d_ws, size_t ws_size,
                              hipStream_t stream) {
    const float* ray        = (const float*)d_in[0];
    const float* emb1_w     = (const float*)d_in[1];
    const float* emb1_b     = (const float*)d_in[2];
    const float* emb2_w     = (const float*)d_in[3];
    const float* emb2_b     = (const float*)d_in[4];
    const float* attn_in_w  = (const float*)d_in[5];
    const float* attn_in_b  = (const float*)d_in[6];
    const float* attn_out_w = (const float*)d_in[7];
    const float* attn_out_b = (const float*)d_in[8];
    const float* ffn1_w     = (const float*)d_in[9];
    const float* ffn1_b     = (const float*)d_in[10];
    const float* ffn2_w     = (const float*)d_in[11];
    const float* ffn2_b     = (const float*)d_in[12];
    const float* exp_w1     = (const float*)d_in[13];
    const float* exp_b1     = (const float*)d_in[14];
    const float* exp_w2     = (const float*)d_in[15];
    const float* exp_b2     = (const float*)d_in[16];
    float* out = (float*)d_out;
    (void)d_ws; (void)ws_size; (void)in_sizes; (void)n_in;  // idx = d_in[17] unused

    k_embed<<<(D4 + 255) / 256, 256, 0, stream>>>(ray, emb1_w, emb1_b, emb2_w, emb2_b);
    // qkv = x @ attn_in_w.T + b   [2, 12288]
    k_gemv_h<<<3 * D4 / 2, 256, 0, stream>>>(attn_in_w, attn_in_b, OFF_X, OFF_QKV, -1, 3 * D4, 0);
    k_attn<<<1, 1024, 0, stream>>>();
    // x += o @ attn_out_w.T + b
    k_gemv_h<<<D4 / 2, 256, 0, stream>>>(attn_out_w, attn_out_b, OFF_O, OFF_X, OFF_X, D4, 0);
    // h = relu(x @ ffn1_w.T + b)
    k_gemv_h<<<D4 / 2, 256, 0, stream>>>(ffn1_w, ffn1_b, OFF_X, OFF_H, -1, D4, 1);
    // x += h @ ffn2_w.T + b
    k_gemv_h<<<D4 / 2, 256, 0, stream>>>(ffn2_w, ffn2_b, OFF_H, OFF_X, OFF_X, D4, 0);
    // g = relu(x @ exp_w1.T + b1)   [2, 8192]
    k_gemv_h<<<E8 / 2, 256, 0, stream>>>(exp_w1, exp_b1, OFF_X, OFF_G, -1, E8, 1);
    // out = mean_l(dot(exp_w2, g[l]) + b2)
    k_expert_out<<<1, 1024, 0, stream>>>(exp_w2, exp_b2, out);
}